// Round 18
// baseline (96.332 us; speedup 1.0000x reference)
//
#include <hip/hip_runtime.h>
#include <hip/hip_bf16.h>
#include <math.h>

#define NQ 256      // D (grid side)
#define CF 128      // channels
#define RS 0.17677669529663687f   // 1/sqrt(32)
#define RSL2E 0.2550565392829014f // RS * log2(e): QK^T in log2 domain
#define NEGB -200.0f              // exp2(s-200) == 0.0f exactly for |s|<50

typedef __attribute__((ext_vector_type(8))) short short8v;   // 8 bf16 = 4 VGPR
typedef __attribute__((ext_vector_type(4))) float f32x4;

static __device__ __forceinline__ unsigned short f2bf(float x) {
  union { float f; unsigned u; } v; v.f = x;
  unsigned r = v.u + 0x7FFFu + ((v.u >> 16) & 1u);  // RNE
  return (unsigned short)(r >> 16);
}

// packed f32x2 -> bf16x2 (compiler emits v_cvt_pk_bf16_f32, hazards handled)
static __device__ __forceinline__ unsigned pack2(float a, float b) {
  __hip_bfloat162 h = __float22bfloat162_rn(make_float2(a, b));
  union { __hip_bfloat162 h; unsigned u; } c; c.h = h; return c.u;
}
static __device__ __forceinline__ unsigned long long pack4(float a, float b,
                                                           float c, float d) {
  return (unsigned long long)pack2(a, b) | ((unsigned long long)pack2(c, d) << 32);
}
static __device__ __forceinline__ uint2 pack4v(float a, float b, float c, float d) {
  uint2 r; r.x = pack2(a, b); r.y = pack2(c, d); return r;
}
static __device__ __forceinline__ short8v cvt8(float4 a, float4 b) {
  union { short8v s; unsigned u[4]; } r;
  r.u[0] = pack2(a.x, a.y); r.u[1] = pack2(a.z, a.w);
  r.u[2] = pack2(b.x, b.y); r.u[3] = pack2(b.z, b.w);
  return r.s;
}
#if __has_builtin(__builtin_amdgcn_exp2f)
#define EXP2F(x) __builtin_amdgcn_exp2f(x)
#else
#define EXP2F(x) exp2f(x)
#endif

#define MFMA16(a, b, c) __builtin_amdgcn_mfma_f32_16x16x32_bf16(a, b, c, 0, 0, 0)

// D-frag (2 packed uint2 pieces: elems c*16+lg*4..+3, c=0,1) -> B-frag
// (elems lg*8..+7) via fixed 4-group lane shuffle: chunk c'=2lg(+1) of the
// B-frag is piece(c'>=4 ? 1:0) of source lane lr+16*(c'&3).
static __device__ __forceinline__ short8v combine8(uint2 p0, uint2 p1,
                                                   int sLo, int sHi, bool lo) {
  int a0 = __shfl((int)p0.x, sLo, 64), a1 = __shfl((int)p0.y, sLo, 64);
  int b0 = __shfl((int)p1.x, sLo, 64), b1 = __shfl((int)p1.y, sLo, 64);
  int c0 = __shfl((int)p0.x, sHi, 64), c1 = __shfl((int)p0.y, sHi, 64);
  int d0 = __shfl((int)p1.x, sHi, 64), d1 = __shfl((int)p1.y, sHi, 64);
  union { short8v s; int u[4]; } r;
  r.u[0] = lo ? a0 : b0;  r.u[1] = lo ? a1 : b1;
  r.u[2] = lo ? c0 : d0;  r.u[3] = lo ? c1 : d1;
  return r.s;
}

// ---------------------------------------------------------------------------
// K0: weight prep. Wt[y][n][k] = bf16(W_y[k][n]), y in {q,k,v,o}. RS*log2e
// folded into Wq. grid (4,16) x 256.
// ---------------------------------------------------------------------------
extern "C" __global__ __launch_bounds__(256) void k_cvt(
    const float* __restrict__ Wq, const float* __restrict__ Wk,
    const float* __restrict__ Wv, const float* __restrict__ Wo,
    unsigned short* __restrict__ Wt)
{
  const int y = blockIdx.x;
  const float* W = (y == 0) ? Wq : (y == 1) ? Wk : (y == 2) ? Wv : Wo;
  unsigned short* dst = Wt + (size_t)y * 16384;
  const float sc = (y == 0) ? RSL2E : 1.0f;
  const int flat = ((int)blockIdx.y * 256 + threadIdx.x) * 4;
  const int k = flat >> 7, n = flat & 127;
  float4 v = *(const float4*)&W[flat];
  dst[(n + 0) * 128 + k] = f2bf(v.x * sc);
  dst[(n + 1) * 128 + k] = f2bf(v.y * sc);
  dst[(n + 2) * 128 + k] = f2bf(v.z * sc);
  dst[(n + 3) * 128 + k] = f2bf(v.w * sc);
}

// ---------------------------------------------------------------------------
// K1: FUSED proj+attention. r17 post-mortem: VGPR=40 is the compiler's own
// choice (AGPR parking), not starvation; the main-loop cost is the P/Q LDS
// round-trip (32 lgkmcnt(0) drains/wave). This version re-fragments P and Q
// via combine8 lane-shuffles (no LDS, no drains, no conflicts). Pb LDS kept
// only for the 2 output-stash round-trips.
// ---------------------------------------------------------------------------
extern "C" __global__ __launch_bounds__(512, 4) void k_attnF(
    const float* __restrict__ ef, const unsigned short* __restrict__ Wt,
    const float* __restrict__ maskg,
    unsigned short* __restrict__ att0, unsigned short* __restrict__ att1)
{
  __shared__ unsigned short S[24832];   // 49664 B -> 3 blocks/CU
  unsigned short* Kl = S;                          // [256][40]
  unsigned short* Vl = S + 10240;                  // [32][280]
  float* biasl = (float*)(S + 19200);              // [256]
  unsigned short* Pb = S + 19712;                  // [8][16][40] (output stash)
  unsigned short* Wl = S;                          // overlay [3][32][136]
  const int cr = blockIdx.x, h = blockIdx.y, mode = blockIdx.z;
  const int t = threadIdx.x, w = t >> 6, l = t & 63;
  const int lr = l & 15, lg = l >> 4;
  unsigned short* Pw = Pb + w * 640;               // wave-private [16][40]
  const int sLo = lr + 16 * ((2 * lg) & 3);
  const int sHi = lr + 16 * ((2 * lg + 1) & 3);
  const bool selLo = (lg < 2);

  // ---- Phase 0: cooperative weight-slice load (head h, Q/K/V) ----
  {
    const int nl = t >> 4, k8 = (t & 15) * 8;
    #pragma unroll
    for (int y = 0; y < 3; ++y) {
      short8v wv = *(const short8v*)&Wt[(size_t)y * 16384
                                        + (size_t)(h * 32 + nl) * 128 + k8];
      *(short8v*)&Wl[y * 4352 + nl * 136 + k8] = wv;
    }
  }
  if (t < 256) {
    const float mv = mode ? maskg[(size_t)cr * NQ + t] : maskg[(size_t)t * NQ + cr];
    biasl[t] = (mv == 0.f) ? NEGB : 0.f;
  }
  __syncthreads();   // Wl + bias visible

  // ---- Phase A: projection MFMAs (wf from LDS); Q,K,V parked in regs ----
  uint2 qOut[2][2], kOut[2][2], vOut[2][2];   // [rt][ct]
  #pragma unroll
  for (int rt = 0; rt < 2; ++rt) {
    short8v af[4];
    {
      const int row = w * 32 + rt * 16 + lr;
      const size_t e = mode ? ((size_t)cr * NQ + row) : ((size_t)row * NQ + cr);
      const float* arow = ef + e * CF;
      #pragma unroll
      for (int kg = 0; kg < 4; ++kg) {
        float4 a = *(const float4*)&arow[kg * 32 + lg * 8];
        float4 b = *(const float4*)&arow[kg * 32 + lg * 8 + 4];
        af[kg] = cvt8(a, b);
      }
    }
    #pragma unroll
    for (int y = 0; y < 3; ++y)
      #pragma unroll
      for (int ct = 0; ct < 2; ++ct) {
        short8v wf[4];
        const unsigned short* wrow = &Wl[y * 4352 + (ct * 16 + lr) * 136];
        #pragma unroll
        for (int kg = 0; kg < 4; ++kg)
          wf[kg] = *(const short8v*)&wrow[kg * 32 + lg * 8];
        f32x4 acc = {0.f, 0.f, 0.f, 0.f};
        #pragma unroll
        for (int kg = 0; kg < 4; ++kg)
          acc = MFMA16(wf[kg], af[kg], acc);
        // D: col(lr)=edge-local, row(lg*4+r)=ch ct*16+lg*4+r
        uint2 p = pack4v(acc[0], acc[1], acc[2], acc[3]);
        if (y == 0)      qOut[rt][ct] = p;
        else if (y == 1) kOut[rt][ct] = p;
        else             vOut[rt][ct] = p;
      }
  }
  __syncthreads();   // all Wl reads complete before Kl/Vl writes

  // ---- Phase B: unpark K/V into Kl/Vl; Q re-fragmented by shuffle ----
  #pragma unroll
  for (int rt = 0; rt < 2; ++rt)
    #pragma unroll
    for (int ct = 0; ct < 2; ++ct) {
      const int kq = w * 32 + rt * 16 + lr;
      *(uint2*)&Kl[kq * 40 + ct * 16 + lg * 4] = kOut[rt][ct];
      const unsigned vx = vOut[rt][ct].x, vy = vOut[rt][ct].y;
      const int ch = ct * 16 + lg * 4;
      Vl[(ch + 0) * 280 + kq] = (unsigned short)vx;
      Vl[(ch + 1) * 280 + kq] = (unsigned short)(vx >> 16);
      Vl[(ch + 2) * 280 + kq] = (unsigned short)vy;
      Vl[(ch + 3) * 280 + kq] = (unsigned short)(vy >> 16);
    }
  short8v qf[2];
  #pragma unroll
  for (int qt = 0; qt < 2; ++qt)
    qf[qt] = combine8(qOut[qt][0], qOut[qt][1], sLo, sHi, selLo);
  __syncthreads();   // Kl/Vl complete block-wide

  // ---- QK^T -> exp2 -> shuffle-refragment -> PV (no LDS round-trip) ----
  f32x4 outv[2][2];   // [qt][dt]: D col=q(lr), row=d(lg*4+r)
  #pragma unroll
  for (int qt = 0; qt < 2; ++qt)
    #pragma unroll
    for (int dt = 0; dt < 2; ++dt) outv[qt][dt] = (f32x4){0.f, 0.f, 0.f, 0.f};
  float psum[2] = {0.f, 0.f};

  #pragma unroll
  for (int kc = 0; kc < 8; ++kc) {
    // hoisted K/V/bias loads, shared across qt
    short8v kf0 = *(const short8v*)&Kl[(kc * 32 + lr) * 40 + lg * 8];
    short8v kf1 = *(const short8v*)&Kl[(kc * 32 + 16 + lr) * 40 + lg * 8];
    f32x4 z0 = *(const f32x4*)&biasl[kc * 32 + lg * 4];
    f32x4 z1 = *(const f32x4*)&biasl[kc * 32 + 16 + lg * 4];
    short8v vf0 = *(const short8v*)&Vl[lr * 280 + kc * 32 + lg * 8];
    short8v vf1 = *(const short8v*)&Vl[(16 + lr) * 280 + kc * 32 + lg * 8];
    #pragma unroll
    for (int qt = 0; qt < 2; ++qt) {
      f32x4 s0 = MFMA16(kf0, qf[qt], z0);   // swapped: col=q, row=k (log2)
      f32x4 s1 = MFMA16(kf1, qf[qt], z1);
      const float p0 = EXP2F(s0[0]), p1 = EXP2F(s0[1]);
      const float p2 = EXP2F(s0[2]), p3 = EXP2F(s0[3]);
      const float p4 = EXP2F(s1[0]), p5 = EXP2F(s1[1]);
      const float p6 = EXP2F(s1[2]), p7 = EXP2F(s1[3]);
      psum[qt] += ((p0 + p1) + (p2 + p3)) + ((p4 + p5) + (p6 + p7));
      uint2 pc0 = pack4v(p0, p1, p2, p3);   // rel keys lg*4..+3
      uint2 pc1 = pack4v(p4, p5, p6, p7);   // rel keys 16+lg*4..+3
      short8v pf = combine8(pc0, pc1, sLo, sHi, selLo);
      outv[qt][0] = MFMA16(vf0, pf, outv[qt][0]);   // swapped: col=q, row=d
      outv[qt][1] = MFMA16(vf1, pf, outv[qt][1]);
    }
  }

  // rowsum: lane-scalar, reduce across the 4 lg-groups (lane bits 4,5)
  float inv[2];
  #pragma unroll
  for (int qt = 0; qt < 2; ++qt) {
    float ssum = psum[qt];
    ssum += __shfl_xor(ssum, 16);
    ssum += __shfl_xor(ssum, 32);
    inv[qt] = 0.5f / ssum;
  }
  // output: qt-sequential stash + coalesced store
  unsigned short* dst = mode ? att1 : att0;
  #pragma unroll
  for (int qt = 0; qt < 2; ++qt) {
    #pragma unroll
    for (int dt = 0; dt < 2; ++dt)
      *(unsigned long long*)&Pw[lr * 40 + dt * 16 + lg * 4] =
          pack4(outv[qt][dt][0] * inv[qt], outv[qt][dt][1] * inv[qt],
                outv[qt][dt][2] * inv[qt], outv[qt][dt][3] * inv[qt]);
    asm volatile("s_waitcnt lgkmcnt(0)" ::: "memory");
    short8v o = *(const short8v*)&Pw[(l >> 2) * 40 + (l & 3) * 8];
    asm volatile("s_waitcnt lgkmcnt(0)" ::: "memory");
    const int q = w * 32 + qt * 16 + (l >> 2);
    const size_t edge = mode ? ((size_t)cr * NQ + q) : ((size_t)q * NQ + cr);
    *(short8v*)&dst[((size_t)h * 65536 + edge) * 32 + (l & 3) * 8] = o;
  }
}

// ---------------------------------------------------------------------------
// K3: MFMA out-proj + bias + residual + LayerNorm + mask -> d_out (f32).
// grid 1024, block 256 (4 waves). launch_bounds(256,2) for VGPR headroom.
// ---------------------------------------------------------------------------
extern "C" __global__ __launch_bounds__(256, 2) void k_finalM(
    float* __restrict__ outb, const float* __restrict__ ef,
    const unsigned short* __restrict__ att0, const unsigned short* __restrict__ att1,
    const unsigned short* __restrict__ Wot, const float* __restrict__ bo,
    const float* __restrict__ gam, const float* __restrict__ bet,
    const float* __restrict__ maskg)
{
  const int t = threadIdx.x, w = t >> 6, l = t & 63;
  const int lr = l & 15, lg = l >> 4;
  const int e0 = blockIdx.x * 64 + w * 16;   // wave strip base

  short8v a0[4], a1[4];
  #pragma unroll
  for (int kg = 0; kg < 4; ++kg) {
    const size_t ab = ((size_t)kg * 65536 + e0 + lr) * 32 + lg * 8;
    a0[kg] = *(const short8v*)&att0[ab];
    a1[kg] = *(const short8v*)&att1[ab];
  }

  f32x4 acc[8];
  #pragma unroll
  for (int nt = 0; nt < 8; ++nt) acc[nt] = (f32x4){0.f, 0.f, 0.f, 0.f};
  #pragma unroll
  for (int nt = 0; nt < 8; ++nt) {
    const unsigned short* wrow = Wot + (size_t)(nt * 16 + lr) * 128;
    #pragma unroll
    for (int kg = 0; kg < 4; ++kg) {
      short8v bf = *(const short8v*)&wrow[kg * 32 + lg * 8];
      acc[nt] = MFMA16(a0[kg], bf, acc[nt]);
      acc[nt] = MFMA16(a1[kg], bf, acc[nt]);
    }
  }

  float bo_l[8], g_l[8], be_l[8];
  #pragma unroll
  for (int nt = 0; nt < 8; ++nt) {
    bo_l[nt] = bo[nt * 16 + lr];
    g_l[nt]  = gam[nt * 16 + lr];
    be_l[nt] = bet[nt * 16 + lr];
  }

  float s[4] = {}, s2[4] = {};
  #pragma unroll
  for (int nt = 0; nt < 8; ++nt)
    #pragma unroll
    for (int r = 0; r < 4; ++r) {
      const float res = ef[(size_t)(e0 + lg * 4 + r) * CF + nt * 16 + lr];
      const float v = acc[nt][r] + bo_l[nt] + res;
      acc[nt][r] = v;
      s[r] += v; s2[r] += v * v;
    }
  float mu[4], rstd[4], mk[4];
  #pragma unroll
  for (int r = 0; r < 4; ++r) {
    float a = s[r], b = s2[r];
    a += __shfl_xor(a, 1); b += __shfl_xor(b, 1);
    a += __shfl_xor(a, 2); b += __shfl_xor(b, 2);
    a += __shfl_xor(a, 4); b += __shfl_xor(b, 4);
    a += __shfl_xor(a, 8); b += __shfl_xor(b, 8);
    mu[r] = a * (1.f / 128.f);
    const float var = b * (1.f / 128.f) - mu[r] * mu[r];
    rstd[r] = rsqrtf(var + 1e-5f);
    mk[r] = maskg[e0 + lg * 4 + r];
  }
  #pragma unroll
  for (int nt = 0; nt < 8; ++nt)
    #pragma unroll
    for (int r = 0; r < 4; ++r) {
      const float yv = ((acc[nt][r] - mu[r]) * rstd[r] * g_l[nt] + be_l[nt]) * mk[r];
      outb[(size_t)(e0 + lg * 4 + r) * CF + nt * 16 + lr] = yv;
    }
}

// ---------------------------------------------------------------------------
extern "C" void kernel_launch(void* const* d_in, const int* in_sizes, int n_in,
                              void* d_out, int out_size, void* d_ws, size_t ws_size,
                              hipStream_t stream)
{
  (void)in_sizes; (void)n_in; (void)out_size; (void)ws_size;
  const float* ef   = (const float*)d_in[0];
  const float* mask = (const float*)d_in[1];
  const float* Wq   = (const float*)d_in[2];
  const float* Wk   = (const float*)d_in[3];
  const float* Wv   = (const float*)d_in[4];
  const float* Wo   = (const float*)d_in[5];
  const float* bo   = (const float*)d_in[6];
  const float* gam  = (const float*)d_in[7];
  const float* bet  = (const float*)d_in[8];
  float* out = (float*)d_out;
  const size_t BUF = (size_t)65536 * 128;       // 8M bf16 elems = 16MB
  unsigned short* Wt   = (unsigned short*)d_ws; // 4 x 16384 = 128KB
  unsigned short* att0 = Wt + 4 * 16384;        // [4][65536][32] bf16 = 16MB
  unsigned short* att1 = att0 + BUF;            // total ~32.1MB

  k_cvt<<<dim3(4, 16), dim3(256), 0, stream>>>(Wq, Wk, Wv, Wo, Wt);
  k_attnF<<<dim3(256, 4, 2), dim3(512), 0, stream>>>(ef, Wt, mask, att0, att1);
  k_finalM<<<dim3(1024), dim3(256), 0, stream>>>(out, ef, att0, att1,
                                                 Wt + 3 * 16384, bo, gam, bet, mask);
}

// Round 22
// 87.614 us; speedup vs baseline: 1.0995x; 1.0995x over previous
//
#include <hip/hip_runtime.h>
#include <hip/hip_bf16.h>
#include <math.h>

#define NQ 256      // D (grid side)
#define CF 128      // channels
#define RS 0.17677669529663687f   // 1/sqrt(32)
#define RSL2E 0.2550565392829014f // RS * log2(e): QK^T in log2 domain
#define NEGB -200.0f              // exp2(s-200) == 0.0f exactly for |s|<50

typedef __attribute__((ext_vector_type(8))) short short8v;   // 8 bf16 = 4 VGPR
typedef __attribute__((ext_vector_type(4))) float f32x4;

static __device__ __forceinline__ unsigned short f2bf(float x) {
  union { float f; unsigned u; } v; v.f = x;
  unsigned r = v.u + 0x7FFFu + ((v.u >> 16) & 1u);  // RNE
  return (unsigned short)(r >> 16);
}

// packed f32x2 -> bf16x2 (compiler emits v_cvt_pk_bf16_f32, hazards handled)
static __device__ __forceinline__ unsigned pack2(float a, float b) {
  __hip_bfloat162 h = __float22bfloat162_rn(make_float2(a, b));
  union { __hip_bfloat162 h; unsigned u; } c; c.h = h; return c.u;
}
static __device__ __forceinline__ unsigned long long pack4(float a, float b,
                                                           float c, float d) {
  return (unsigned long long)pack2(a, b) | ((unsigned long long)pack2(c, d) << 32);
}
static __device__ __forceinline__ uint2 pack4v(float a, float b, float c, float d) {
  uint2 r; r.x = pack2(a, b); r.y = pack2(c, d); return r;
}
static __device__ __forceinline__ short8v cvt8(float4 a, float4 b) {
  union { short8v s; unsigned u[4]; } r;
  r.u[0] = pack2(a.x, a.y); r.u[1] = pack2(a.z, a.w);
  r.u[2] = pack2(b.x, b.y); r.u[3] = pack2(b.z, b.w);
  return r.s;
}
#if __has_builtin(__builtin_amdgcn_exp2f)
#define EXP2F(x) __builtin_amdgcn_exp2f(x)
#else
#define EXP2F(x) exp2f(x)
#endif

#define MFMA16(a, b, c) __builtin_amdgcn_mfma_f32_16x16x32_bf16(a, b, c, 0, 0, 0)

// ---------------------------------------------------------------------------
// K0: weight prep. Wt[y][n][k] = bf16(W_y[k][n]), y in {q,k,v,o}. RS*log2e
// folded into Wq. grid (4,16) x 256.
// ---------------------------------------------------------------------------
extern "C" __global__ __launch_bounds__(256) void k_cvt(
    const float* __restrict__ Wq, const float* __restrict__ Wk,
    const float* __restrict__ Wv, const float* __restrict__ Wo,
    unsigned short* __restrict__ Wt)
{
  const int y = blockIdx.x;
  const float* W = (y == 0) ? Wq : (y == 1) ? Wk : (y == 2) ? Wv : Wo;
  unsigned short* dst = Wt + (size_t)y * 16384;
  const float sc = (y == 0) ? RSL2E : 1.0f;
  const int flat = ((int)blockIdx.y * 256 + threadIdx.x) * 4;
  const int k = flat >> 7, n = flat & 127;
  float4 v = *(const float4*)&W[flat];
  dst[(n + 0) * 128 + k] = f2bf(v.x * sc);
  dst[(n + 1) * 128 + k] = f2bf(v.y * sc);
  dst[(n + 2) * 128 + k] = f2bf(v.z * sc);
  dst[(n + 3) * 128 + k] = f2bf(v.w * sc);
}

// ---------------------------------------------------------------------------
// K1: FUSED proj+attention (r17 structure — best known) + XCD-aware grid
// swizzle. r17 counters: dur*bw == FETCH+WRITE => HBM-bound at 1.9 TB/s,
// FETCH 91MB (~3x ef): the 4 head-blocks of each (cr,mode) re-read the
// same 128KB ef slice via different XCDs. Swizzle: id = 32*(g>>3) + 8*h
// + (g&7), g = cr+256*mode — the 4 h-variants differ by 8 => same XCD
// (id%8), adjacent dispatch => ef slice shared in that XCD's L2.
// ---------------------------------------------------------------------------
extern "C" __global__ __launch_bounds__(512, 4) void k_attnF(
    const float* __restrict__ ef, const unsigned short* __restrict__ Wt,
    const float* __restrict__ maskg,
    unsigned short* __restrict__ att0, unsigned short* __restrict__ att1)
{
  __shared__ unsigned short S[24832];   // 49664 B -> 3 blocks/CU
  unsigned short* Kl = S;                          // [256][40]
  unsigned short* Vl = S + 10240;                  // [32][280]
  float* biasl = (float*)(S + 19200);              // [256]
  unsigned short* Pb = S + 19712;                  // [8][16][40]
  unsigned short* Wl = S;                          // overlay [3][32][136]
  // XCD swizzle decode (bijective on [0,2048))
  const int id = blockIdx.x;
  const int h = (id >> 3) & 3;
  const int g = ((id >> 5) << 3) | (id & 7);
  const int cr = g & 255, mode = g >> 8;
  const int t = threadIdx.x, w = t >> 6, l = t & 63;
  const int lr = l & 15, lg = l >> 4;
  unsigned short* Pw = Pb + w * 640;               // wave-private [16][40]

  // ---- Phase 0: cooperative weight-slice load (head h, Q/K/V) ----
  {
    const int nl = t >> 4, k8 = (t & 15) * 8;
    #pragma unroll
    for (int y = 0; y < 3; ++y) {
      short8v wv = *(const short8v*)&Wt[(size_t)y * 16384
                                        + (size_t)(h * 32 + nl) * 128 + k8];
      *(short8v*)&Wl[y * 4352 + nl * 136 + k8] = wv;
    }
  }
  if (t < 256) {
    const float mv = mode ? maskg[(size_t)cr * NQ + t] : maskg[(size_t)t * NQ + cr];
    biasl[t] = (mv == 0.f) ? NEGB : 0.f;
  }
  __syncthreads();   // Wl + bias visible

  // ---- Phase A: projection MFMAs (wf from LDS); Q,K,V parked in regs ----
  uint2 qOut[2][2], kOut[2][2], vOut[2][2];   // [rt][ct]
  #pragma unroll
  for (int rt = 0; rt < 2; ++rt) {
    short8v af[4];
    {
      const int row = w * 32 + rt * 16 + lr;
      const size_t e = mode ? ((size_t)cr * NQ + row) : ((size_t)row * NQ + cr);
      const float* arow = ef + e * CF;
      #pragma unroll
      for (int kg = 0; kg < 4; ++kg) {
        float4 a = *(const float4*)&arow[kg * 32 + lg * 8];
        float4 b = *(const float4*)&arow[kg * 32 + lg * 8 + 4];
        af[kg] = cvt8(a, b);
      }
    }
    #pragma unroll
    for (int y = 0; y < 3; ++y)
      #pragma unroll
      for (int ct = 0; ct < 2; ++ct) {
        short8v wf[4];
        const unsigned short* wrow = &Wl[y * 4352 + (ct * 16 + lr) * 136];
        #pragma unroll
        for (int kg = 0; kg < 4; ++kg)
          wf[kg] = *(const short8v*)&wrow[kg * 32 + lg * 8];
        f32x4 acc = {0.f, 0.f, 0.f, 0.f};
        #pragma unroll
        for (int kg = 0; kg < 4; ++kg)
          acc = MFMA16(wf[kg], af[kg], acc);
        // D: col(lr)=edge-local, row(lg*4+r)=ch ct*16+lg*4+r
        uint2 p = pack4v(acc[0], acc[1], acc[2], acc[3]);
        if (y == 0)      qOut[rt][ct] = p;
        else if (y == 1) kOut[rt][ct] = p;
        else             vOut[rt][ct] = p;
      }
  }
  __syncthreads();   // all Wl reads complete before Kl/Vl writes

  // ---- Phase B: unpark K/V into Kl/Vl; Q round-trip per qt ----
  #pragma unroll
  for (int rt = 0; rt < 2; ++rt)
    #pragma unroll
    for (int ct = 0; ct < 2; ++ct) {
      const int kq = w * 32 + rt * 16 + lr;
      *(uint2*)&Kl[kq * 40 + ct * 16 + lg * 4] = kOut[rt][ct];
      const unsigned vx = vOut[rt][ct].x, vy = vOut[rt][ct].y;
      const int ch = ct * 16 + lg * 4;
      Vl[(ch + 0) * 280 + kq] = (unsigned short)vx;
      Vl[(ch + 1) * 280 + kq] = (unsigned short)(vx >> 16);
      Vl[(ch + 2) * 280 + kq] = (unsigned short)vy;
      Vl[(ch + 3) * 280 + kq] = (unsigned short)(vy >> 16);
    }
  short8v qf[2];
  #pragma unroll
  for (int qt = 0; qt < 2; ++qt) {   // wave-private Pb: in-order DS, safe
    *(uint2*)&Pw[lr * 40 + lg * 4] = qOut[qt][0];
    *(uint2*)&Pw[lr * 40 + 16 + lg * 4] = qOut[qt][1];
    asm volatile("s_waitcnt lgkmcnt(0)" ::: "memory");
    qf[qt] = *(const short8v*)&Pw[lr * 40 + lg * 8];
    asm volatile("s_waitcnt lgkmcnt(0)" ::: "memory");
  }
  __syncthreads();   // Kl/Vl complete block-wide

  // ---- QK^T -> exp2 -> PV (qt-sequential P round-trip) ----
  f32x4 outv[2][2];   // [qt][dt]: D col=q(lr), row=d(lg*4+r)
  #pragma unroll
  for (int qt = 0; qt < 2; ++qt)
    #pragma unroll
    for (int dt = 0; dt < 2; ++dt) outv[qt][dt] = (f32x4){0.f, 0.f, 0.f, 0.f};
  float psum[2] = {0.f, 0.f};

  #pragma unroll
  for (int kc = 0; kc < 8; ++kc) {
    // hoisted K/V/bias loads, shared across qt
    short8v kf0 = *(const short8v*)&Kl[(kc * 32 + lr) * 40 + lg * 8];
    short8v kf1 = *(const short8v*)&Kl[(kc * 32 + 16 + lr) * 40 + lg * 8];
    f32x4 z0 = *(const f32x4*)&biasl[kc * 32 + lg * 4];
    f32x4 z1 = *(const f32x4*)&biasl[kc * 32 + 16 + lg * 4];
    short8v vf0 = *(const short8v*)&Vl[lr * 280 + kc * 32 + lg * 8];
    short8v vf1 = *(const short8v*)&Vl[(16 + lr) * 280 + kc * 32 + lg * 8];
    #pragma unroll
    for (int qt = 0; qt < 2; ++qt) {
      f32x4 s0 = MFMA16(kf0, qf[qt], z0);   // swapped: col=q, row=k (log2)
      float p0 = EXP2F(s0[0]), p1 = EXP2F(s0[1]);
      float p2 = EXP2F(s0[2]), p3 = EXP2F(s0[3]);
      psum[qt] += (p0 + p1) + (p2 + p3);
      *(unsigned long long*)&Pw[lr * 40 + lg * 4] = pack4(p0, p1, p2, p3);
      f32x4 s1 = MFMA16(kf1, qf[qt], z1);
      p0 = EXP2F(s1[0]); p1 = EXP2F(s1[1]);
      p2 = EXP2F(s1[2]); p3 = EXP2F(s1[3]);
      psum[qt] += (p0 + p1) + (p2 + p3);
      *(unsigned long long*)&Pw[lr * 40 + 16 + lg * 4] = pack4(p0, p1, p2, p3);
      asm volatile("s_waitcnt lgkmcnt(0)" ::: "memory");
      short8v pf = *(const short8v*)&Pw[lr * 40 + lg * 8];
      asm volatile("s_waitcnt lgkmcnt(0)" ::: "memory");
      outv[qt][0] = MFMA16(vf0, pf, outv[qt][0]);   // swapped: col=q, row=d
      outv[qt][1] = MFMA16(vf1, pf, outv[qt][1]);
    }
  }

  // rowsum: lane-scalar, reduce across the 4 lg-groups (lane bits 4,5)
  float inv[2];
  #pragma unroll
  for (int qt = 0; qt < 2; ++qt) {
    float ssum = psum[qt];
    ssum += __shfl_xor(ssum, 16);
    ssum += __shfl_xor(ssum, 32);
    inv[qt] = 0.5f / ssum;
  }
  // output: qt-sequential stash + coalesced store
  unsigned short* dst = mode ? att1 : att0;
  #pragma unroll
  for (int qt = 0; qt < 2; ++qt) {
    #pragma unroll
    for (int dt = 0; dt < 2; ++dt)
      *(unsigned long long*)&Pw[lr * 40 + dt * 16 + lg * 4] =
          pack4(outv[qt][dt][0] * inv[qt], outv[qt][dt][1] * inv[qt],
                outv[qt][dt][2] * inv[qt], outv[qt][dt][3] * inv[qt]);
    asm volatile("s_waitcnt lgkmcnt(0)" ::: "memory");
    short8v o = *(const short8v*)&Pw[(l >> 2) * 40 + (l & 3) * 8];
    asm volatile("s_waitcnt lgkmcnt(0)" ::: "memory");
    const int q = w * 32 + qt * 16 + (l >> 2);
    const size_t edge = mode ? ((size_t)cr * NQ + q) : ((size_t)q * NQ + cr);
    *(short8v*)&dst[((size_t)h * 65536 + edge) * 32 + (l & 3) * 8] = o;
  }
}

// ---------------------------------------------------------------------------
// K3: MFMA out-proj + bias + residual + LayerNorm + mask -> d_out (f32).
// grid 1024, block 256 (4 waves). launch_bounds(256,2) for VGPR headroom.
// ---------------------------------------------------------------------------
extern "C" __global__ __launch_bounds__(256, 2) void k_finalM(
    float* __restrict__ outb, const float* __restrict__ ef,
    const unsigned short* __restrict__ att0, const unsigned short* __restrict__ att1,
    const unsigned short* __restrict__ Wot, const float* __restrict__ bo,
    const float* __restrict__ gam, const float* __restrict__ bet,
    const float* __restrict__ maskg)
{
  const int t = threadIdx.x, w = t >> 6, l = t & 63;
  const int lr = l & 15, lg = l >> 4;
  const int e0 = blockIdx.x * 64 + w * 16;   // wave strip base

  short8v a0[4], a1[4];
  #pragma unroll
  for (int kg = 0; kg < 4; ++kg) {
    const size_t ab = ((size_t)kg * 65536 + e0 + lr) * 32 + lg * 8;
    a0[kg] = *(const short8v*)&att0[ab];
    a1[kg] = *(const short8v*)&att1[ab];
  }

  f32x4 acc[8];
  #pragma unroll
  for (int nt = 0; nt < 8; ++nt) acc[nt] = (f32x4){0.f, 0.f, 0.f, 0.f};
  #pragma unroll
  for (int nt = 0; nt < 8; ++nt) {
    const unsigned short* wrow = Wot + (size_t)(nt * 16 + lr) * 128;
    #pragma unroll
    for (int kg = 0; kg < 4; ++kg) {
      short8v bf = *(const short8v*)&wrow[kg * 32 + lg * 8];
      acc[nt] = MFMA16(a0[kg], bf, acc[nt]);
      acc[nt] = MFMA16(a1[kg], bf, acc[nt]);
    }
  }

  float bo_l[8], g_l[8], be_l[8];
  #pragma unroll
  for (int nt = 0; nt < 8; ++nt) {
    bo_l[nt] = bo[nt * 16 + lr];
    g_l[nt]  = gam[nt * 16 + lr];
    be_l[nt] = bet[nt * 16 + lr];
  }

  float s[4] = {}, s2[4] = {};
  #pragma unroll
  for (int nt = 0; nt < 8; ++nt)
    #pragma unroll
    for (int r = 0; r < 4; ++r) {
      const float res = ef[(size_t)(e0 + lg * 4 + r) * CF + nt * 16 + lr];
      const float v = acc[nt][r] + bo_l[nt] + res;
      acc[nt][r] = v;
      s[r] += v; s2[r] += v * v;
    }
  float mu[4], rstd[4], mk[4];
  #pragma unroll
  for (int r = 0; r < 4; ++r) {
    float a = s[r], b = s2[r];
    a += __shfl_xor(a, 1); b += __shfl_xor(b, 1);
    a += __shfl_xor(a, 2); b += __shfl_xor(b, 2);
    a += __shfl_xor(a, 4); b += __shfl_xor(b, 4);
    a += __shfl_xor(a, 8); b += __shfl_xor(b, 8);
    mu[r] = a * (1.f / 128.f);
    const float var = b * (1.f / 128.f) - mu[r] * mu[r];
    rstd[r] = rsqrtf(var + 1e-5f);
    mk[r] = maskg[e0 + lg * 4 + r];
  }
  #pragma unroll
  for (int nt = 0; nt < 8; ++nt)
    #pragma unroll
    for (int r = 0; r < 4; ++r) {
      const float yv = ((acc[nt][r] - mu[r]) * rstd[r] * g_l[nt] + be_l[nt]) * mk[r];
      outb[(size_t)(e0 + lg * 4 + r) * CF + nt * 16 + lr] = yv;
    }
}

// ---------------------------------------------------------------------------
extern "C" void kernel_launch(void* const* d_in, const int* in_sizes, int n_in,
                              void* d_out, int out_size, void* d_ws, size_t ws_size,
                              hipStream_t stream)
{
  (void)in_sizes; (void)n_in; (void)out_size; (void)ws_size;
  const float* ef   = (const float*)d_in[0];
  const float* mask = (const float*)d_in[1];
  const float* Wq   = (const float*)d_in[2];
  const float* Wk   = (const float*)d_in[3];
  const float* Wv   = (const float*)d_in[4];
  const float* Wo   = (const float*)d_in[5];
  const float* bo   = (const float*)d_in[6];
  const float* gam  = (const float*)d_in[7];
  const float* bet  = (const float*)d_in[8];
  float* out = (float*)d_out;
  const size_t BUF = (size_t)65536 * 128;       // 8M bf16 elems = 16MB
  unsigned short* Wt   = (unsigned short*)d_ws; // 4 x 16384 = 128KB
  unsigned short* att0 = Wt + 4 * 16384;        // [4][65536][32] bf16 = 16MB
  unsigned short* att1 = att0 + BUF;            // total ~32.1MB

  k_cvt<<<dim3(4, 16), dim3(256), 0, stream>>>(Wq, Wk, Wv, Wo, Wt);
  k_attnF<<<dim3(2048), dim3(512), 0, stream>>>(ef, Wt, mask, att0, att1);
  k_finalM<<<dim3(1024), dim3(256), 0, stream>>>(out, ef, att0, att1,
                                                 Wt + 3 * 16384, bo, gam, bet, mask);
}

// Round 23
// 85.573 us; speedup vs baseline: 1.1257x; 1.0238x over previous
//
#include <hip/hip_runtime.h>
#include <hip/hip_bf16.h>
#include <math.h>

#define NQ 256      // D (grid side)
#define CF 128      // channels
#define RS 0.17677669529663687f   // 1/sqrt(32)
#define RSL2E 0.2550565392829014f // RS * log2(e): QK^T in log2 domain
#define NEGB -200.0f              // exp2(s-200) == 0.0f exactly for |s|<50

typedef __attribute__((ext_vector_type(8))) short short8v;   // 8 bf16 = 4 VGPR
typedef __attribute__((ext_vector_type(4))) float f32x4;

static __device__ __forceinline__ unsigned short f2bf(float x) {
  union { float f; unsigned u; } v; v.f = x;
  unsigned r = v.u + 0x7FFFu + ((v.u >> 16) & 1u);  // RNE
  return (unsigned short)(r >> 16);
}

// packed f32x2 -> bf16x2 (compiler emits v_cvt_pk_bf16_f32, hazards handled)
static __device__ __forceinline__ unsigned pack2(float a, float b) {
  __hip_bfloat162 h = __float22bfloat162_rn(make_float2(a, b));
  union { __hip_bfloat162 h; unsigned u; } c; c.h = h; return c.u;
}
static __device__ __forceinline__ unsigned long long pack4(float a, float b,
                                                           float c, float d) {
  return (unsigned long long)pack2(a, b) | ((unsigned long long)pack2(c, d) << 32);
}
static __device__ __forceinline__ uint2 pack4v(float a, float b, float c, float d) {
  uint2 r; r.x = pack2(a, b); r.y = pack2(c, d); return r;
}
static __device__ __forceinline__ short8v cvt8(float4 a, float4 b) {
  union { short8v s; unsigned u[4]; } r;
  r.u[0] = pack2(a.x, a.y); r.u[1] = pack2(a.z, a.w);
  r.u[2] = pack2(b.x, b.y); r.u[3] = pack2(b.z, b.w);
  return r.s;
}
#if __has_builtin(__builtin_amdgcn_exp2f)
#define EXP2F(x) __builtin_amdgcn_exp2f(x)
#else
#define EXP2F(x) exp2f(x)
#endif

#define MFMA16(a, b, c) __builtin_amdgcn_mfma_f32_16x16x32_bf16(a, b, c, 0, 0, 0)

// ---------------------------------------------------------------------------
// K0: weight prep. Wt[y][n][k] = bf16(W_y[k][n]), y in {q,k,v,o}. RS*log2e
// folded into Wq. grid (4,16) x 256.
// ---------------------------------------------------------------------------
extern "C" __global__ __launch_bounds__(256) void k_cvt(
    const float* __restrict__ Wq, const float* __restrict__ Wk,
    const float* __restrict__ Wv, const float* __restrict__ Wo,
    unsigned short* __restrict__ Wt)
{
  const int y = blockIdx.x;
  const float* W = (y == 0) ? Wq : (y == 1) ? Wk : (y == 2) ? Wv : Wo;
  unsigned short* dst = Wt + (size_t)y * 16384;
  const float sc = (y == 0) ? RSL2E : 1.0f;
  const int flat = ((int)blockIdx.y * 256 + threadIdx.x) * 4;
  const int k = flat >> 7, n = flat & 127;
  float4 v = *(const float4*)&W[flat];
  dst[(n + 0) * 128 + k] = f2bf(v.x * sc);
  dst[(n + 1) * 128 + k] = f2bf(v.y * sc);
  dst[(n + 2) * 128 + k] = f2bf(v.z * sc);
  dst[(n + 3) * 128 + k] = f2bf(v.w * sc);
}

// ---------------------------------------------------------------------------
// K1: FUSED proj+attention + XCD swizzle (r22: FETCH 91->34MB confirmed).
// r22 post-mortem: dur unchanged => not BW-bound; issue/serialization-bound.
// This round: REMOVE all hand-written s_waitcnt lgkmcnt(0) drains on the
// wave-private Pw round-trips. DS is in-order per wave (write->read of the
// same LDS needs no wait) and the compiler auto-inserts precise counted
// lgkmcnt before dependent MFMA use — the full drains were flushing the
// whole DS queue (incl. prefetched Kl/Vl loads) 36x/wave.
// ---------------------------------------------------------------------------
extern "C" __global__ __launch_bounds__(512, 4) void k_attnF(
    const float* __restrict__ ef, const unsigned short* __restrict__ Wt,
    const float* __restrict__ maskg,
    unsigned short* __restrict__ att0, unsigned short* __restrict__ att1)
{
  __shared__ unsigned short S[24832];   // 49664 B -> 3 blocks/CU
  unsigned short* Kl = S;                          // [256][40]
  unsigned short* Vl = S + 10240;                  // [32][280]
  float* biasl = (float*)(S + 19200);              // [256]
  unsigned short* Pb = S + 19712;                  // [8][16][40]
  unsigned short* Wl = S;                          // overlay [3][32][136]
  // XCD swizzle decode (bijective on [0,2048))
  const int id = blockIdx.x;
  const int h = (id >> 3) & 3;
  const int g = ((id >> 5) << 3) | (id & 7);
  const int cr = g & 255, mode = g >> 8;
  const int t = threadIdx.x, w = t >> 6, l = t & 63;
  const int lr = l & 15, lg = l >> 4;
  unsigned short* Pw = Pb + w * 640;               // wave-private [16][40]

  // ---- Phase 0: cooperative weight-slice load (head h, Q/K/V) ----
  {
    const int nl = t >> 4, k8 = (t & 15) * 8;
    #pragma unroll
    for (int y = 0; y < 3; ++y) {
      short8v wv = *(const short8v*)&Wt[(size_t)y * 16384
                                        + (size_t)(h * 32 + nl) * 128 + k8];
      *(short8v*)&Wl[y * 4352 + nl * 136 + k8] = wv;
    }
  }
  if (t < 256) {
    const float mv = mode ? maskg[(size_t)cr * NQ + t] : maskg[(size_t)t * NQ + cr];
    biasl[t] = (mv == 0.f) ? NEGB : 0.f;
  }
  __syncthreads();   // Wl + bias visible

  // ---- Phase A: projection MFMAs (wf from LDS); Q,K,V parked in regs ----
  uint2 qOut[2][2], kOut[2][2], vOut[2][2];   // [rt][ct]
  #pragma unroll
  for (int rt = 0; rt < 2; ++rt) {
    short8v af[4];
    {
      const int row = w * 32 + rt * 16 + lr;
      const size_t e = mode ? ((size_t)cr * NQ + row) : ((size_t)row * NQ + cr);
      const float* arow = ef + e * CF;
      #pragma unroll
      for (int kg = 0; kg < 4; ++kg) {
        float4 a = *(const float4*)&arow[kg * 32 + lg * 8];
        float4 b = *(const float4*)&arow[kg * 32 + lg * 8 + 4];
        af[kg] = cvt8(a, b);
      }
    }
    #pragma unroll
    for (int y = 0; y < 3; ++y)
      #pragma unroll
      for (int ct = 0; ct < 2; ++ct) {
        short8v wf[4];
        const unsigned short* wrow = &Wl[y * 4352 + (ct * 16 + lr) * 136];
        #pragma unroll
        for (int kg = 0; kg < 4; ++kg)
          wf[kg] = *(const short8v*)&wrow[kg * 32 + lg * 8];
        f32x4 acc = {0.f, 0.f, 0.f, 0.f};
        #pragma unroll
        for (int kg = 0; kg < 4; ++kg)
          acc = MFMA16(wf[kg], af[kg], acc);
        // D: col(lr)=edge-local, row(lg*4+r)=ch ct*16+lg*4+r
        uint2 p = pack4v(acc[0], acc[1], acc[2], acc[3]);
        if (y == 0)      qOut[rt][ct] = p;
        else if (y == 1) kOut[rt][ct] = p;
        else             vOut[rt][ct] = p;
      }
  }
  __syncthreads();   // all Wl reads complete before Kl/Vl writes

  // ---- Phase B: unpark K/V into Kl/Vl; Q round-trip per qt ----
  #pragma unroll
  for (int rt = 0; rt < 2; ++rt)
    #pragma unroll
    for (int ct = 0; ct < 2; ++ct) {
      const int kq = w * 32 + rt * 16 + lr;
      *(uint2*)&Kl[kq * 40 + ct * 16 + lg * 4] = kOut[rt][ct];
      const unsigned vx = vOut[rt][ct].x, vy = vOut[rt][ct].y;
      const int ch = ct * 16 + lg * 4;
      Vl[(ch + 0) * 280 + kq] = (unsigned short)vx;
      Vl[(ch + 1) * 280 + kq] = (unsigned short)(vx >> 16);
      Vl[(ch + 2) * 280 + kq] = (unsigned short)vy;
      Vl[(ch + 3) * 280 + kq] = (unsigned short)(vy >> 16);
    }
  short8v qf[2];
  #pragma unroll
  for (int qt = 0; qt < 2; ++qt) {   // wave-private Pw: DS in-order, no drain
    *(uint2*)&Pw[lr * 40 + lg * 4] = qOut[qt][0];
    *(uint2*)&Pw[lr * 40 + 16 + lg * 4] = qOut[qt][1];
    qf[qt] = *(const short8v*)&Pw[lr * 40 + lg * 8];
  }
  __syncthreads();   // Kl/Vl complete block-wide

  // ---- QK^T -> exp2 -> PV (qt-sequential P round-trip, no drains) ----
  f32x4 outv[2][2];   // [qt][dt]: D col=q(lr), row=d(lg*4+r)
  #pragma unroll
  for (int qt = 0; qt < 2; ++qt)
    #pragma unroll
    for (int dt = 0; dt < 2; ++dt) outv[qt][dt] = (f32x4){0.f, 0.f, 0.f, 0.f};
  float psum[2] = {0.f, 0.f};

  #pragma unroll
  for (int kc = 0; kc < 8; ++kc) {
    // hoisted K/V/bias loads, shared across qt
    short8v kf0 = *(const short8v*)&Kl[(kc * 32 + lr) * 40 + lg * 8];
    short8v kf1 = *(const short8v*)&Kl[(kc * 32 + 16 + lr) * 40 + lg * 8];
    f32x4 z0 = *(const f32x4*)&biasl[kc * 32 + lg * 4];
    f32x4 z1 = *(const f32x4*)&biasl[kc * 32 + 16 + lg * 4];
    short8v vf0 = *(const short8v*)&Vl[lr * 280 + kc * 32 + lg * 8];
    short8v vf1 = *(const short8v*)&Vl[(16 + lr) * 280 + kc * 32 + lg * 8];
    #pragma unroll
    for (int qt = 0; qt < 2; ++qt) {
      f32x4 s0 = MFMA16(kf0, qf[qt], z0);   // swapped: col=q, row=k (log2)
      float p0 = EXP2F(s0[0]), p1 = EXP2F(s0[1]);
      float p2 = EXP2F(s0[2]), p3 = EXP2F(s0[3]);
      psum[qt] += (p0 + p1) + (p2 + p3);
      *(unsigned long long*)&Pw[lr * 40 + lg * 4] = pack4(p0, p1, p2, p3);
      f32x4 s1 = MFMA16(kf1, qf[qt], z1);
      p0 = EXP2F(s1[0]); p1 = EXP2F(s1[1]);
      p2 = EXP2F(s1[2]); p3 = EXP2F(s1[3]);
      psum[qt] += (p0 + p1) + (p2 + p3);
      *(unsigned long long*)&Pw[lr * 40 + 16 + lg * 4] = pack4(p0, p1, p2, p3);
      short8v pf = *(const short8v*)&Pw[lr * 40 + lg * 8];
      outv[qt][0] = MFMA16(vf0, pf, outv[qt][0]);   // swapped: col=q, row=d
      outv[qt][1] = MFMA16(vf1, pf, outv[qt][1]);
    }
  }

  // rowsum: lane-scalar, reduce across the 4 lg-groups (lane bits 4,5)
  float inv[2];
  #pragma unroll
  for (int qt = 0; qt < 2; ++qt) {
    float ssum = psum[qt];
    ssum += __shfl_xor(ssum, 16);
    ssum += __shfl_xor(ssum, 32);
    inv[qt] = 0.5f / ssum;
  }
  // output: qt-sequential stash + coalesced store (no drains)
  unsigned short* dst = mode ? att1 : att0;
  #pragma unroll
  for (int qt = 0; qt < 2; ++qt) {
    #pragma unroll
    for (int dt = 0; dt < 2; ++dt)
      *(unsigned long long*)&Pw[lr * 40 + dt * 16 + lg * 4] =
          pack4(outv[qt][dt][0] * inv[qt], outv[qt][dt][1] * inv[qt],
                outv[qt][dt][2] * inv[qt], outv[qt][dt][3] * inv[qt]);
    short8v o = *(const short8v*)&Pw[(l >> 2) * 40 + (l & 3) * 8];
    const int q = w * 32 + qt * 16 + (l >> 2);
    const size_t edge = mode ? ((size_t)cr * NQ + q) : ((size_t)q * NQ + cr);
    *(short8v*)&dst[((size_t)h * 65536 + edge) * 32 + (l & 3) * 8] = o;
  }
}

// ---------------------------------------------------------------------------
// K3: MFMA out-proj + bias + residual + LayerNorm + mask -> d_out (f32).
// grid 1024, block 256 (4 waves). launch_bounds(256,2) for VGPR headroom.
// ---------------------------------------------------------------------------
extern "C" __global__ __launch_bounds__(256, 2) void k_finalM(
    float* __restrict__ outb, const float* __restrict__ ef,
    const unsigned short* __restrict__ att0, const unsigned short* __restrict__ att1,
    const unsigned short* __restrict__ Wot, const float* __restrict__ bo,
    const float* __restrict__ gam, const float* __restrict__ bet,
    const float* __restrict__ maskg)
{
  const int t = threadIdx.x, w = t >> 6, l = t & 63;
  const int lr = l & 15, lg = l >> 4;
  const int e0 = blockIdx.x * 64 + w * 16;   // wave strip base

  short8v a0[4], a1[4];
  #pragma unroll
  for (int kg = 0; kg < 4; ++kg) {
    const size_t ab = ((size_t)kg * 65536 + e0 + lr) * 32 + lg * 8;
    a0[kg] = *(const short8v*)&att0[ab];
    a1[kg] = *(const short8v*)&att1[ab];
  }

  f32x4 acc[8];
  #pragma unroll
  for (int nt = 0; nt < 8; ++nt) acc[nt] = (f32x4){0.f, 0.f, 0.f, 0.f};
  #pragma unroll
  for (int nt = 0; nt < 8; ++nt) {
    const unsigned short* wrow = Wot + (size_t)(nt * 16 + lr) * 128;
    #pragma unroll
    for (int kg = 0; kg < 4; ++kg) {
      short8v bf = *(const short8v*)&wrow[kg * 32 + lg * 8];
      acc[nt] = MFMA16(a0[kg], bf, acc[nt]);
      acc[nt] = MFMA16(a1[kg], bf, acc[nt]);
    }
  }

  float bo_l[8], g_l[8], be_l[8];
  #pragma unroll
  for (int nt = 0; nt < 8; ++nt) {
    bo_l[nt] = bo[nt * 16 + lr];
    g_l[nt]  = gam[nt * 16 + lr];
    be_l[nt] = bet[nt * 16 + lr];
  }

  float s[4] = {}, s2[4] = {};
  #pragma unroll
  for (int nt = 0; nt < 8; ++nt)
    #pragma unroll
    for (int r = 0; r < 4; ++r) {
      const float res = ef[(size_t)(e0 + lg * 4 + r) * CF + nt * 16 + lr];
      const float v = acc[nt][r] + bo_l[nt] + res;
      acc[nt][r] = v;
      s[r] += v; s2[r] += v * v;
    }
  float mu[4], rstd[4], mk[4];
  #pragma unroll
  for (int r = 0; r < 4; ++r) {
    float a = s[r], b = s2[r];
    a += __shfl_xor(a, 1); b += __shfl_xor(b, 1);
    a += __shfl_xor(a, 2); b += __shfl_xor(b, 2);
    a += __shfl_xor(a, 4); b += __shfl_xor(b, 4);
    a += __shfl_xor(a, 8); b += __shfl_xor(b, 8);
    mu[r] = a * (1.f / 128.f);
    const float var = b * (1.f / 128.f) - mu[r] * mu[r];
    rstd[r] = rsqrtf(var + 1e-5f);
    mk[r] = maskg[e0 + lg * 4 + r];
  }
  #pragma unroll
  for (int nt = 0; nt < 8; ++nt)
    #pragma unroll
    for (int r = 0; r < 4; ++r) {
      const float yv = ((acc[nt][r] - mu[r]) * rstd[r] * g_l[nt] + be_l[nt]) * mk[r];
      outb[(size_t)(e0 + lg * 4 + r) * CF + nt * 16 + lr] = yv;
    }
}

// ---------------------------------------------------------------------------
extern "C" void kernel_launch(void* const* d_in, const int* in_sizes, int n_in,
                              void* d_out, int out_size, void* d_ws, size_t ws_size,
                              hipStream_t stream)
{
  (void)in_sizes; (void)n_in; (void)out_size; (void)ws_size;
  const float* ef   = (const float*)d_in[0];
  const float* mask = (const float*)d_in[1];
  const float* Wq   = (const float*)d_in[2];
  const float* Wk   = (const float*)d_in[3];
  const float* Wv   = (const float*)d_in[4];
  const float* Wo   = (const float*)d_in[5];
  const float* bo   = (const float*)d_in[6];
  const float* gam  = (const float*)d_in[7];
  const float* bet  = (const float*)d_in[8];
  float* out = (float*)d_out;
  const size_t BUF = (size_t)65536 * 128;       // 8M bf16 elems = 16MB
  unsigned short* Wt   = (unsigned short*)d_ws; // 4 x 16384 = 128KB
  unsigned short* att0 = Wt + 4 * 16384;        // [4][65536][32] bf16 = 16MB
  unsigned short* att1 = att0 + BUF;            // total ~32.1MB

  k_cvt<<<dim3(4, 16), dim3(256), 0, stream>>>(Wq, Wk, Wv, Wo, Wt);
  k_attnF<<<dim3(2048), dim3(512), 0, stream>>>(ef, Wt, mask, att0, att1);
  k_finalM<<<dim3(1024), dim3(256), 0, stream>>>(out, ef, att0, att1,
                                                 Wt + 3 * 16384, bo, gam, bet, mask);
}